// Round 8
// baseline (128.166 us; speedup 1.0000x reference)
//
#include <hip/hip_runtime.h>
#include <hip/hip_bf16.h>
#include <math.h>

// NT-Xent loss, N=4096, D=256, symmetric-GEMM version.
// loss = (1/2N) * sum_i [ 2 + log( sum_{j != i} exp(2*dot_ij - 2) ) - 2*dot(zn_i, zn_pair(i)) ]
//
// ROUND-8 MODEL (fits rounds 0-7): both kernels are WAVE-COUNT bound
// (~185-190 waves/us device-wide, per-wave fixed cost; all pipes <25% busy).
// Fix = fewer, fatter waves:
// K1: 128 blocks (512 waves), each wave normalizes 16 rows (grid-stride,
//     next-row prefetch). Was 2048 blocks / 8192 waves ~= 40+ us hidden cost.
// K2: 520 blocks (2080 waves) x 4 consecutive 128x128 tiles each. Per-step
//     T14 reg-staged prefetch (round-7-verified) extended ACROSS tile
//     boundaries, so no round-4-style serialization; 2 blocks/CU co-resident.
//     Fused epilogue per tile; fence-free ticket finalize (verified r1/2/4)
//     replaces the k_finalize dispatch.

using short8  = __attribute__((ext_vector_type(8))) short;
using floatx4 = __attribute__((ext_vector_type(4))) float;

constexpr int TWO_N = 8192;
constexpr int DIM   = 256;
constexpr int NB    = 64;                 // 8192/128 tile blocks per side
constexpr int NTRI  = NB * (NB + 1) / 2;  // 2080 tiles
constexpr int TPB   = 4;                  // tiles per block
constexpr int NBLK  = NTRI / TPB;         // 520 blocks
constexpr float INV2N = 1.0f / 8192.0f;

__device__ static inline unsigned short f2bf(float f) {
  unsigned u = __float_as_uint(f);
  return (unsigned short)((u + 0x7fffu + ((u >> 16) & 1u)) >> 16);  // RNE
}

__device__ static inline void tri_decode(int u, int& ib, int& jb) {
  int j = (int)((sqrtf(8.0f * (float)u + 1.0f) - 1.0f) * 0.5f);
  while ((j + 1) * (j + 2) / 2 <= u) ++j;
  while (j * (j + 1) / 2 > u) --j;
  jb = j; ib = u - j * (j + 1) / 2;
}

// ---------------- K1: normalize + cast to bf16 (512 waves x 16 rows) ----------------
__global__ __launch_bounds__(256) void k_normalize(
    const float* __restrict__ zi, const float* __restrict__ zj,
    __hip_bfloat16* __restrict__ zn, float* __restrict__ rowtotal,
    float* __restrict__ out, unsigned* __restrict__ ticket)
{
  if (blockIdx.x == 0 && threadIdx.x == 0) { out[0] = 0.0f; ticket[0] = 0u; }
  if (blockIdx.x < 32) rowtotal[blockIdx.x * 256 + threadIdx.x] = 0.0f;

  const int lane = threadIdx.x & 63;
  const int wave = threadIdx.x >> 6;
  const int gw   = blockIdx.x * 4 + wave;   // 0..511 global wave id

  // row index in concat order: gw + it*512 (zi half: it<8, zj half: it>=8,
  // since 4096 = 8*512 the zj offset folds into the same formula).
  auto srcptr = [&](int it) -> const float* {
    return ((it < 8) ? zi : zj) + (size_t)(gw + (it & 7) * 512) * DIM;
  };

  float4 v = reinterpret_cast<const float4*>(srcptr(0))[lane];
#pragma unroll
  for (int it = 0; it < 16; ++it) {
    float4 vn;
    if (it < 15) vn = reinterpret_cast<const float4*>(srcptr(it + 1))[lane];
    float ss = v.x * v.x + v.y * v.y + v.z * v.z + v.w * v.w;
#pragma unroll
    for (int m = 32; m >= 1; m >>= 1) ss += __shfl_xor(ss, m, 64);
    float inv = 1.0f / fmaxf(sqrtf(ss), 1e-8f);
    ushort4 o;
    o.x = f2bf(v.x * inv); o.y = f2bf(v.y * inv);
    o.z = f2bf(v.z * inv); o.w = f2bf(v.w * inv);
    reinterpret_cast<ushort4*>(zn + (size_t)(gw + it * 512) * DIM)[lane] = o;
    v = vn;
  }
}

// ---------------- K2: multi-tile triangular GEMM + fused epilogue + ticket ----------------
// block 256 = 4 waves in 2x2; wave owns 64x64 (4x4 of 16x16x32 accumulators).
// LDS tiles [128][64] bf16, 16B-slot XOR swizzle: phys_slot = logical ^ (row&7).
// Staging: T14 reg prefetch (issue-early) -> compute -> __syncthreads (vmcnt
// drain lands after compute) -> ds_write -> __syncthreads. Cross-tile: at a
// tile's last K-step, prefetch the NEXT tile's first K-step.
__global__ __launch_bounds__(256) void k_simexp(
    const __hip_bfloat16* __restrict__ Z, float* __restrict__ rowtotal,
    float* __restrict__ out, unsigned* __restrict__ ticket)
{
  __shared__ __align__(16) __hip_bfloat16 As[128 * 64];
  __shared__ __align__(16) __hip_bfloat16 Bs[128 * 64];
  __shared__ float rowsum[128];
  __shared__ float colsum[128];
  __shared__ float finsum[4];
  __shared__ int lastflag;

  const int tid  = threadIdx.x;
  const int lane = tid & 63;
  const int wave = tid >> 6;
  const int wm   = wave >> 1;   // output row half
  const int wn   = wave & 1;    // output col half
  const bool diagwave = (wm == wn);

  const int lane7 = lane & 7;
  const int sub   = lane >> 3;               // 0..7 subrow within 8-row segment
  const int gkoff = ((lane7 ^ sub) << 3);    // swizzled logical 16B slot to fetch
  const int q     = lane >> 4;               // 0..3
  const int c16   = lane & 15;

  if (tid < 128) { rowsum[tid] = 0.0f; colsum[tid] = 0.0f; }

  __hip_bfloat16* lbase = ((wave < 2) ? As : Bs) + (wave & 1) * 64 * 64;
  short8 r[8];

  auto prefetch = [&](const __hip_bfloat16* gb, int k0) {
#pragma unroll
    for (int c = 0; c < 8; ++c)
      r[c] = *reinterpret_cast<const short8*>(
          gb + (size_t)(c * 8 + sub) * DIM + k0 + gkoff);
  };
  auto store_regs = [&]() {
#pragma unroll
    for (int c = 0; c < 8; ++c)
      *reinterpret_cast<short8*>(lbase + c * 512 + lane * 8) = r[c];
  };

  // tile 0 decode + prologue stage (kk=0)
  int ib, jb;
  tri_decode(blockIdx.x * TPB, ib, jb);
  const __hip_bfloat16* gbase =
      Z + (size_t)(((wave < 2) ? ib * 128 : jb * 128) + (wave & 1) * 64) * DIM;
  prefetch(gbase, 0);
  store_regs();
  __syncthreads();

  for (int t = 0; t < TPB; ++t) {
    const int u = blockIdx.x * TPB + t;
    const bool diagblk = (ib == jb);
    const bool pairblk = (jb == ib + 32);
    const int i0 = ib * 128;
    const int j0 = jb * 128;
    int ibn = ib, jbn = jb;

    floatx4 acc[4][4] = {};

#pragma unroll
    for (int kk = 0; kk < 4; ++kk) {
      const bool last_gs = (t == TPB - 1) && (kk == 3);
      // issue next step's global loads FIRST; they land during compute(kk)
      if (!last_gs) {
        if (kk < 3) {
          prefetch(gbase, (kk + 1) * 64);
        } else {
          tri_decode(u + 1, ibn, jbn);
          gbase = Z + (size_t)(((wave < 2) ? ibn * 128 : jbn * 128) +
                               (wave & 1) * 64) * DIM;
          prefetch(gbase, 0);
        }
        __builtin_amdgcn_sched_barrier(0);  // pin loads (don't sink past compute)
      }

      // compute step kk from LDS
#pragma unroll
      for (int ks = 0; ks < 2; ++ks) {
        const int phys = (ks * 4 + q) ^ lane7;  // physical 16B slot for this lane
        short8 a[4], b[4];
#pragma unroll
        for (int mt = 0; mt < 4; ++mt)
          a[mt] = *reinterpret_cast<const short8*>(
              As + (wm * 64 + mt * 16 + c16) * 64 + phys * 8);
#pragma unroll
        for (int nt = 0; nt < 4; ++nt)
          b[nt] = *reinterpret_cast<const short8*>(
              Bs + (wn * 64 + nt * 16 + c16) * 64 + phys * 8);
#pragma unroll
        for (int mt = 0; mt < 4; ++mt)
#pragma unroll
          for (int nt = 0; nt < 4; ++nt)
            acc[mt][nt] = __builtin_amdgcn_mfma_f32_16x16x32_bf16(
                a[mt], b[nt], acc[mt][nt], 0, 0, 0);
      }

      __syncthreads();   // vmcnt drain lands AFTER compute; all waves done reading
      if (!last_gs) {
        store_regs();
        __syncthreads(); // lgkm-only drain: writes visible for next compute
      }
    }

    // ---- epilogue for tile t ----
    // C/D layout: col = lane&15 (within nt-tile), row = q*4 + reg (within mt-tile).
    float colacc[4] = {0.f, 0.f, 0.f, 0.f};
    float pc = 0.f;

#pragma unroll
    for (int mt = 0; mt < 4; ++mt) {
#pragma unroll
      for (int reg = 0; reg < 4; ++reg) {
        const bool onquad = (c16 == q * 4 + reg);  // lane holds a subtile-diag elem
        float s = 0.0f;
#pragma unroll
        for (int nt = 0; nt < 4; ++nt) {
          float e = __expf(2.0f * acc[mt][nt][reg] - 2.0f);
          bool skip = diagblk && diagwave && (nt == mt) && onquad;  // true self-sim
          s += skip ? 0.0f : e;
          colacc[nt] += e;
        }
        if (pairblk && diagwave && onquad) pc += acc[mt][mt][reg];  // pair dot
        s += __shfl_xor(s, 1, 64);
        s += __shfl_xor(s, 2, 64);
        s += __shfl_xor(s, 4, 64);
        s += __shfl_xor(s, 8, 64);
        if (c16 == 0)
          atomicAdd(&rowsum[wm * 64 + mt * 16 + q * 4 + reg], s);
      }
    }

    if (!diagblk) {
#pragma unroll
      for (int nt = 0; nt < 4; ++nt) {
        float cs = colacc[nt];
        cs += __shfl_xor(cs, 16, 64);
        cs += __shfl_xor(cs, 32, 64);
        if (lane < 16) atomicAdd(&colsum[wn * 64 + nt * 16 + lane], cs);
      }
    }

    if (pairblk && diagwave) {
#pragma unroll
      for (int m = 32; m >= 1; m >>= 1) pc += __shfl_xor(pc, m, 64);
      // each pair diag elem covers rows i and i+4096: loss += -2*(2*dot) per pair
      if (lane == 0) atomicAdd(out, -4.0f * pc * INV2N);
    }

    __syncthreads();   // rowsum/colsum LDS atomics complete before flush
    if (tid < 128) {
      atomicAdd(&rowtotal[i0 + tid], rowsum[tid]);
      rowsum[tid] = 0.0f;
      if (!diagblk) atomicAdd(&rowtotal[j0 + tid], colsum[tid]);
      colsum[tid] = 0.0f;
    }
    // next epilogue's LDS atomics are separated from this zeroing by the
    // next tile's K-step barriers -- no extra sync needed here.

    ib = ibn; jb = jbn;
  }

  // ---- fence-free ticket finalize (verified r1/r2/r4): last block reduces ----
  // __syncthreads drains vmcnt(0): this block's device-scope rowtotal atomics
  // reached the coherence point before the ticket bump.
  __syncthreads();
  if (tid == 0) lastflag = (atomicAdd(ticket, 1u) == (unsigned)(NBLK - 1)) ? 1 : 0;
  __syncthreads();
  if (lastflag) {
    __threadfence();      // acquire side; ONE block only (cheap)
    float v = 0.0f;
#pragma unroll 4
    for (int rr = tid; rr < TWO_N; rr += 256) {
      float tv = __hip_atomic_load(&rowtotal[rr], __ATOMIC_RELAXED,
                                   __HIP_MEMORY_SCOPE_AGENT);
      v += 2.0f + __logf(tv);
    }
#pragma unroll
    for (int m = 32; m >= 1; m >>= 1) v += __shfl_xor(v, m, 64);
    if (lane == 0) finsum[wave] = v;
    __syncthreads();
    if (tid == 0)
      atomicAdd(out, (finsum[0] + finsum[1] + finsum[2] + finsum[3]) * INV2N);
  }
}

// ---------------- launch ----------------
extern "C" void kernel_launch(void* const* d_in, const int* in_sizes, int n_in,
                              void* d_out, int out_size, void* d_ws, size_t ws_size,
                              hipStream_t stream) {
  const float* zi = (const float*)d_in[0];
  const float* zj = (const float*)d_in[1];
  float* out = (float*)d_out;

  __hip_bfloat16* zn = (__hip_bfloat16*)d_ws;                        // 8192*256*2 = 4 MB
  float* rowtotal = (float*)((char*)d_ws + (size_t)TWO_N * DIM * 2); // 8192*4 = 32 KB
  unsigned* ticket = (unsigned*)((char*)d_ws + (size_t)TWO_N * DIM * 2 + (size_t)TWO_N * 4);

  k_normalize<<<dim3(128), dim3(256), 0, stream>>>(zi, zj, zn, rowtotal, out, ticket);
  k_simexp<<<dim3(NBLK), dim3(256), 0, stream>>>(zn, rowtotal, out, ticket);
}